// Round 1
// baseline (308.645 us; speedup 1.0000x reference)
//
#include <hip/hip_runtime.h>
#include <math.h>

// Squeeze-Excitation: x(32,256,128,128) f32; w1(16,256); w2(256,16)
// out = x * sigmoid(relu(mean_hw(x) @ w1^T) @ w2^T) broadcast per (b,c) plane.

#define PLANE   16384   // 128*128 elements per (b,c) plane
#define PLANE4  4096    // in float4 units
#define CH      256
#define CR      16

// ---------------- Kernel 1: global average pool per plane ----------------
__global__ __launch_bounds__(256) void se_pool(const float* __restrict__ x,
                                               float* __restrict__ y,
                                               int nplanes) {
    const int plane = blockIdx.x;           // forward order
    const int t = threadIdx.x;
    const float4* xp = reinterpret_cast<const float4*>(x) + (size_t)plane * PLANE4;

    float sum = 0.f;
#pragma unroll
    for (int k = 0; k < 16; ++k) {
        float4 v = xp[t + k * 256];
        sum += (v.x + v.y) + (v.z + v.w);
    }
    // wave-64 shuffle reduce
#pragma unroll
    for (int off = 32; off > 0; off >>= 1)
        sum += __shfl_down(sum, off, 64);

    __shared__ float ws[4];
    const int lane = t & 63, wid = t >> 6;
    if (lane == 0) ws[wid] = sum;
    __syncthreads();
    if (t == 0) {
        float tot = (ws[0] + ws[1]) + (ws[2] + ws[3]);
        y[plane] = tot * (1.0f / (float)PLANE);
    }
}

// ---------------- Kernel 2: tiny MLP (256 -> 16 relu -> 256 sigmoid) -----
__global__ __launch_bounds__(256) void se_excite(const float* __restrict__ y,
                                                 const float* __restrict__ w1,
                                                 const float* __restrict__ w2,
                                                 float* __restrict__ s) {
    const int b = blockIdx.x;     // batch index
    const int t = threadIdx.x;    // channel index
    __shared__ float yrow[CH];
    __shared__ float h[CR];

    yrow[t] = y[b * CH + t];
    __syncthreads();

    if (t < CR) {
        float acc = 0.f;
        for (int c = 0; c < CH; ++c)
            acc += yrow[c] * w1[t * CH + c];
        h[t] = fmaxf(acc, 0.f);
    }
    __syncthreads();

    float acc = 0.f;
#pragma unroll
    for (int j = 0; j < CR; ++j)
        acc += h[j] * w2[t * CR + j];
    s[b * CH + t] = 1.0f / (1.0f + expf(-acc));
}

// ---------------- Kernel 3: broadcast scale (reverse order for L3 reuse) -
__global__ __launch_bounds__(256) void se_scale(const float* __restrict__ x,
                                                const float* __restrict__ s,
                                                float* __restrict__ out,
                                                int nplanes) {
    // Walk planes in REVERSE of the pool pass: the tail of x is still hot
    // in the 256 MiB Infinity Cache when this kernel starts.
    const int plane = nplanes - 1 - blockIdx.x;
    const int t = threadIdx.x;
    const float sc = s[plane];
    const float4* xp = reinterpret_cast<const float4*>(x) + (size_t)plane * PLANE4;
    float4*       op = reinterpret_cast<float4*>(out)     + (size_t)plane * PLANE4;

#pragma unroll
    for (int k = 0; k < 16; ++k) {
        float4 v = xp[t + k * 256];
        v.x *= sc; v.y *= sc; v.z *= sc; v.w *= sc;
        op[t + k * 256] = v;
    }
}

extern "C" void kernel_launch(void* const* d_in, const int* in_sizes, int n_in,
                              void* d_out, int out_size, void* d_ws, size_t ws_size,
                              hipStream_t stream) {
    const float* x  = (const float*)d_in[0];   // (32,256,128,128)
    const float* w1 = (const float*)d_in[1];   // (16,256)
    const float* w2 = (const float*)d_in[2];   // (256,16)
    float* out = (float*)d_out;

    const int nplanes = in_sizes[0] / PLANE;   // 32*256 = 8192
    const int B = nplanes / CH;                // 32

    float* y = (float*)d_ws;                   // nplanes floats
    float* s = y + nplanes;                    // nplanes floats

    se_pool  <<<nplanes, 256, 0, stream>>>(x, y, nplanes);
    se_excite<<<B,       256, 0, stream>>>(y, w1, w2, s);
    se_scale <<<nplanes, 256, 0, stream>>>(x, s, out, nplanes);
}

// Round 2
// 291.519 us; speedup vs baseline: 1.0587x; 1.0587x over previous
//
#include <hip/hip_runtime.h>
#include <math.h>

// Squeeze-Excitation: x(32,256,128,128) f32; w1(16,256); w2(256,16)
// out = x * sigmoid(relu(mean_hw(x) @ w1^T) @ w2^T), scale per (b,c) plane.
//
// Strategy: process in chunks of 8 batch images (8*256 planes = 128 MiB),
// which fit in the 256 MiB Infinity Cache. Per chunk:
//   1) se_pool  : read chunk from HBM (allocates in L3), per-plane means
//   2) se_scale : re-read chunk (L3 hit), fused tiny-MLP per block,
//                 NON-TEMPORAL stores for out (don't evict the chunk)
// HBM traffic: x read once + out written once ~= 1.07 GiB (vs 1.61 naive).

#define PLANE   16384   // 128*128
#define PLANE4  4096    // in float4
#define CH      256
#define CR      16
#define BPC     8       // batches per chunk (8*16MiB = 128 MiB <= L3)

typedef float f32x4 __attribute__((ext_vector_type(4)));

// ---------------- Kernel 1: per-plane mean over a chunk -------------------
__global__ __launch_bounds__(256) void se_pool(const float* __restrict__ x,
                                               float* __restrict__ y,
                                               int plane0) {
    const int plane = plane0 + blockIdx.x;
    const int t = threadIdx.x;
    const f32x4* xp = reinterpret_cast<const f32x4*>(x) + (size_t)plane * PLANE4;

    float sum = 0.f;
#pragma unroll
    for (int k = 0; k < 16; ++k) {
        f32x4 v = xp[t + k * 256];
        sum += (v.x + v.y) + (v.z + v.w);
    }
#pragma unroll
    for (int off = 32; off > 0; off >>= 1)
        sum += __shfl_down(sum, off, 64);

    __shared__ float ws[4];
    const int lane = t & 63, wid = t >> 6;
    if (lane == 0) ws[wid] = sum;
    __syncthreads();
    if (t == 0) {
        float tot = (ws[0] + ws[1]) + (ws[2] + ws[3]);
        y[plane] = tot * (1.0f / (float)PLANE);
    }
}

// ------- Kernel 2: fused MLP (redundant per block) + scale, NT stores -----
__global__ __launch_bounds__(256) void se_scale(const float* __restrict__ x,
                                                const float* __restrict__ y,
                                                const float* __restrict__ w1,
                                                const float* __restrict__ w2,
                                                float* __restrict__ out,
                                                int plane0) {
    const int plane = plane0 + blockIdx.x;
    const int b = plane >> 8;        // /CH
    const int c = plane & (CH - 1);  // %CH
    const int t = threadIdx.x;

    __shared__ float yrow[CH];
    __shared__ float h[CR];
    __shared__ float s_sh;

    yrow[t] = y[b * CH + t];
    __syncthreads();

    if (t < CR) {
        float acc = 0.f;
#pragma unroll 8
        for (int k = 0; k < CH; ++k)
            acc += yrow[k] * w1[t * CH + k];
        h[t] = fmaxf(acc, 0.f);
    }
    __syncthreads();

    if (t == 0) {
        float acc = 0.f;
#pragma unroll
        for (int j = 0; j < CR; ++j)
            acc += h[j] * w2[c * CR + j];
        s_sh = 1.0f / (1.0f + expf(-acc));
    }
    __syncthreads();

    const float sc = s_sh;
    const f32x4* xp = reinterpret_cast<const f32x4*>(x)   + (size_t)plane * PLANE4;
    f32x4*       op = reinterpret_cast<f32x4*>(out)       + (size_t)plane * PLANE4;

#pragma unroll
    for (int k = 0; k < 16; ++k) {
        f32x4 v = xp[t + k * 256];   // expect L3 hit (chunk just pooled)
        v *= sc;
        __builtin_nontemporal_store(v, &op[t + k * 256]);  // don't pollute L3
    }
}

extern "C" void kernel_launch(void* const* d_in, const int* in_sizes, int n_in,
                              void* d_out, int out_size, void* d_ws, size_t ws_size,
                              hipStream_t stream) {
    const float* x  = (const float*)d_in[0];   // (32,256,128,128)
    const float* w1 = (const float*)d_in[1];   // (16,256)
    const float* w2 = (const float*)d_in[2];   // (256,16)
    float* out = (float*)d_out;

    const int nplanes = in_sizes[0] / PLANE;   // 8192
    const int B = nplanes / CH;                // 32
    float* y = (float*)d_ws;                   // nplanes floats

    const int planes_per_chunk = BPC * CH;     // 2048
    const int nchunks = B / BPC;               // 4

    for (int ck = 0; ck < nchunks; ++ck) {
        const int plane0 = ck * planes_per_chunk;
        se_pool <<<planes_per_chunk, 256, 0, stream>>>(x, y, plane0);
        se_scale<<<planes_per_chunk, 256, 0, stream>>>(x, y, w1, w2, out, plane0);
    }
}